// Round 8
// baseline (2587.659 us; speedup 1.0000x reference)
//
#include <hip/hip_runtime.h>
#include <cstdint>
#include <cstddef>

#define B_DIM 128
#define T_LEN 2048
#define C_DIM 128
#define NSTEP (T_LEN - 1)   // 2047 backpointer rows, s = 0..2046
#define NS4   512           // ceil(2047/4) dword-rows per batch

// Skew: F(x) = x + 8*(x>>5). 32-float chunk c sits at 40c; the 4 chunks'
// ds_read_b128 streams hit disjoint bank quartets (perfect 32-bank perm).
#define FSKEW(x) ((x) + 8 * ((x) >> 5))

// Barrier WITHOUT vmcnt drain (R7: worth ~130 cyc/step). Cross-wave LDS
// visibility needs lgkmcnt(0) only; pot prefetches / bp stores stay in
// flight across the barrier.
#define LDS_BARRIER() asm volatile("s_waitcnt lgkmcnt(0)\n\ts_barrier" ::: "memory")

// 32 trans values as NAMED SCALARS (R5/R7: VGPR=88, resident).
#define TR_LIST(X) \
    X(0)  X(1)  X(2)  X(3)  X(4)  X(5)  X(6)  X(7)  \
    X(8)  X(9)  X(10) X(11) X(12) X(13) X(14) X(15) \
    X(16) X(17) X(18) X(19) X(20) X(21) X(22) X(23) \
    X(24) X(25) X(26) X(27) X(28) X(29) X(30) X(31)

// Forward Viterbi. TWO batches per block: 1024 threads = 16 waves = 4/SIMD.
// R7 model: step = ~580 cyc issue + ~1150 cyc serialized latency (barrier ->
// ds_read -> dep chains -> ds_write -> barrier) with 2 waves/SIMD in lockstep.
// Co-locating a second, independent batch group overlaps group A's latency
// with group B's issue: ~1300-1500 cyc per step for TWO batches.
// Within a batch (tidb = tid&511): wave w owns j in [16w,16w+16); lane l:
// j = 16w + (l>>2), d = l&3, i in [32d,32d+32). Per step: 32 adds +
// adjacent-pair tournament (first-index exact) + 2 DPP quad_perm merges
// (0xB1, 0x4E; partner-with-lower-d wins ties) + d==0 writes alpha/bp.
__global__ __launch_bounds__(1024)
__attribute__((amdgpu_waves_per_eu(4, 4)))
void viterbi_fwd(
    const float* __restrict__ pot,
    const float* __restrict__ trans,
    unsigned* __restrict__ bp4,        // [NS4][B][C] dwords, 4 steps packed/dword
    int* __restrict__ lastTag)
{
    const int tid   = threadIdx.x;
    const int bb    = tid >> 9;            // batch-group within block (0/1)
    const int tidb  = tid & 511;
    const int batch = 2 * blockIdx.x + bb;
    const int w     = tidb >> 6;
    const int l     = tid & 63;
    const int d     = l & 3;               // i-chunk: [32d, 32d+32)
    const int j     = 16 * w + (l >> 2);
    const int fj    = FSKEW(j);
    const int ib    = 32 * d;

    __shared__ __align__(16) float alphabuf[2][2][160];   // [bb][parity][160]

#define DECL_TR(K) float tr_##K = trans[(ib + (K)) * C_DIM + j];
    TR_LIST(DECL_TR)
#undef DECL_TR

    const float* potb = pot + (size_t)batch * T_LEN * C_DIM;

    // alpha0 = pot[:,0] into buf[1] (step t=1 reads buf[t&1] = buf[1])
    if (tidb < C_DIM) alphabuf[bb][1][FSKEW(tidb)] = potb[tidb];

    // pot prefetch queue, depth 4 (d==0 lanes only consume it)
    float pq0 = 0.f, pq1 = 0.f, pq2 = 0.f, pq3 = 0.f;
    if (d == 0) {
        pq0 = potb[1 * C_DIM + j];
        pq1 = potb[2 * C_DIM + j];
        pq2 = potb[3 * C_DIM + j];
        pq3 = potb[4 * C_DIM + j];
    }
    unsigned pack = 0;
    __syncthreads();   // init barrier: full drain once, fine

#define ADD_TR(K) s_[K] = a_[K] + tr_##K;

#define STEP(T_, C_, PQ_)                                                     \
    {                                                                         \
        const float* ac_ = &alphabuf[bb][(T_) & 1][40 * d];                   \
        float a_[32];                                                         \
        _Pragma("unroll")                                                     \
        for (int e_ = 0; e_ < 8; ++e_)                                        \
            *(float4*)&a_[4 * e_] = *(const float4*)&ac_[4 * e_];             \
        float s_[32];                                                         \
        TR_LIST(ADD_TR)                                                       \
        float v16_[16]; int x16_[16];                                         \
        _Pragma("unroll")                                                     \
        for (int p_ = 0; p_ < 16; ++p_) {                                     \
            const bool g_ = s_[2 * p_ + 1] > s_[2 * p_];                      \
            v16_[p_] = g_ ? s_[2 * p_ + 1] : s_[2 * p_];                      \
            x16_[p_] = g_ ? 2 * p_ + 1 : 2 * p_;                              \
        }                                                                     \
        float v8_[8]; int x8_[8];                                             \
        _Pragma("unroll")                                                     \
        for (int p_ = 0; p_ < 8; ++p_) {                                      \
            const bool g_ = v16_[2 * p_ + 1] > v16_[2 * p_];                  \
            v8_[p_] = g_ ? v16_[2 * p_ + 1] : v16_[2 * p_];                   \
            x8_[p_] = g_ ? x16_[2 * p_ + 1] : x16_[2 * p_];                   \
        }                                                                     \
        float v4_[4]; int x4_[4];                                             \
        _Pragma("unroll")                                                     \
        for (int p_ = 0; p_ < 4; ++p_) {                                      \
            const bool g_ = v8_[2 * p_ + 1] > v8_[2 * p_];                    \
            v4_[p_] = g_ ? v8_[2 * p_ + 1] : v8_[2 * p_];                     \
            x4_[p_] = g_ ? x8_[2 * p_ + 1] : x8_[2 * p_];                     \
        }                                                                     \
        float v2_[2]; int x2_[2];                                             \
        _Pragma("unroll")                                                     \
        for (int p_ = 0; p_ < 2; ++p_) {                                      \
            const bool g_ = v4_[2 * p_ + 1] > v4_[2 * p_];                    \
            v2_[p_] = g_ ? v4_[2 * p_ + 1] : v4_[2 * p_];                     \
            x2_[p_] = g_ ? x4_[2 * p_ + 1] : x4_[2 * p_];                     \
        }                                                                     \
        const bool gf_ = v2_[1] > v2_[0];                                     \
        float v_ = gf_ ? v2_[1] : v2_[0];                                     \
        int   x_ = ib + (gf_ ? x2_[1] : x2_[0]);                              \
        /* DPP quad_perm merge across d. Round 1: xor 1 (ctrl 0xB1) */        \
        {                                                                     \
            const float pv_ = __int_as_float(__builtin_amdgcn_update_dpp(     \
                0, __float_as_int(v_), 0xB1, 0xF, 0xF, true));                \
            const int   px_ = __builtin_amdgcn_update_dpp(                    \
                0, x_, 0xB1, 0xF, 0xF, true);                                 \
            const bool  pl_ = d & 1;                                          \
            const bool  tk_ = (pv_ > v_) || (pl_ && (pv_ == v_));             \
            if (tk_) { v_ = pv_; x_ = px_; }                                  \
        }                                                                     \
        /* Round 2: xor 2 (ctrl 0x4E) */                                      \
        {                                                                     \
            const float pv_ = __int_as_float(__builtin_amdgcn_update_dpp(     \
                0, __float_as_int(v_), 0x4E, 0xF, 0xF, true));                \
            const int   px_ = __builtin_amdgcn_update_dpp(                    \
                0, x_, 0x4E, 0xF, 0xF, true);                                 \
            const bool  pl_ = (d >> 1) & 1;                                   \
            const bool  tk_ = (pv_ > v_) || (pl_ && (pv_ == v_));             \
            if (tk_) { v_ = pv_; x_ = px_; }                                  \
        }                                                                     \
        if (d == 0) {                                                         \
            alphabuf[bb][((T_) + 1) & 1][fj] = v_ + (PQ_);                    \
            pack |= (unsigned)x_ << (8 * (C_));                               \
            if ((C_) == 3) {                                                  \
                bp4[((size_t)(((T_) - 1) >> 2) * B_DIM + batch) * C_DIM + j]  \
                    = pack;                                                   \
                pack = 0;                                                     \
            }                                                                 \
            if ((T_) + 4 < T_LEN) PQ_ = potb[((T_) + 4) * C_DIM + j];         \
        }                                                                     \
        LDS_BARRIER();                                                        \
    }

    // main loop: t = 1 .. 2044 (511 groups of 4, complete bp dwords)
    for (int t = 1; t < 2045; t += 4) {
        STEP(t + 0, 0, pq0)
        STEP(t + 1, 1, pq1)
        STEP(t + 2, 2, pq2)
        STEP(t + 3, 3, pq3)
    }
    // tail: t = 2045, 2046, 2047 (s = 2044..2046 -> bytes 0..2 of dword 511)
    STEP(2045, 0, pq0)
    STEP(2046, 1, pq1)
    STEP(2047, 2, pq2)
    if (d == 0)
        bp4[((size_t)511 * B_DIM + batch) * C_DIM + j] = pack;
#undef STEP
#undef ADD_TR

    // last_tag = first-index argmax of final alpha (buf[0]); wave 0 of each group
    if (tidb < 64) {
        const float* af = alphabuf[bb][0];
        const float v0 = af[FSKEW(tidb)];
        const float v1 = af[FSKEW(tidb + 64)];
        float v = v0; int x = tidb;
        if (v1 > v0) { v = v1; x = tidb + 64; }
#pragma unroll
        for (int mk = 1; mk < 64; mk <<= 1) {
            const float pv = __shfl_xor(v, mk);
            const int   px = __shfl_xor(x, mk);
            if (pv > v || (pv == v && px < x)) { v = pv; x = px; }
        }
        if (tidb == 0) lastTag[batch] = x;
    }
}

// Backtrack. One wave per batch. cur is wave-uniform, so the chase uses
// v_readlane (VALU latency, ~15 cyc/step) instead of ds_bpermute (~60+).
// Rows (128 dwords) live 2/lane: qa = dwords 0..63, qb = 64..127.
// 4-deep named-register prefetch queue hides HBM latency of row loads.
__global__ __launch_bounds__(64, 1) void viterbi_bwd(
    const unsigned* __restrict__ bp4,
    const int* __restrict__ lastTag,
    float* __restrict__ out)
{
    const int b = blockIdx.x;
    const int l = threadIdx.x;
    float* outb = out + (size_t)b * T_LEN;

    unsigned qa0 = 0, qb0 = 0, qa1 = 0, qb1 = 0,
             qa2 = 0, qb2 = 0, qa3 = 0, qb3 = 0;

    auto ld = [&](int s4, unsigned& A, unsigned& B) {
        if (s4 >= 0) {
            const unsigned* r = bp4 + ((size_t)s4 * B_DIM + b) * C_DIM;
            A = r[l];
            B = r[l + 64];
        }
    };
    ld(511, qa0, qb0);
    ld(510, qa1, qb1);
    ld(509, qa2, qb2);
    ld(508, qa3, qb3);

    int cur = lastTag[b];   // uniform across the wave

    auto ext = [&](unsigned rA, unsigned rB, int c, int byte) -> int {
        const int lane = c & 63;                       // uniform
        const int vA = __builtin_amdgcn_readlane((int)rA, lane);
        const int vB = __builtin_amdgcn_readlane((int)rB, lane);
        const int v = (c & 64) ? vB : vA;
        return (v >> (byte * 8)) & 0xFF;
    };

    // peel s4 = 511: s = 2046..2044 (byte 3 unused); out[2047] = lastTag
    {
        const unsigned rA = qa0, rB = qb0;
        const float t3 = (float)cur;               // out[2047]
        cur = ext(rA, rB, cur, 2); const float t2 = (float)cur;
        cur = ext(rA, rB, cur, 1); const float t1 = (float)cur;
        cur = ext(rA, rB, cur, 0); const float t0 = (float)cur;
        if (l == 0) *(float4*)(outb + 4 * 511) = make_float4(t0, t1, t2, t3);
        qa0 = qa1; qb0 = qb1; qa1 = qa2; qb1 = qb2; qa2 = qa3; qb2 = qb3;
        ld(507, qa3, qb3);
    }

    for (int s4 = 510; s4 >= 0; --s4) {
        const unsigned rA = qa0, rB = qb0;
        cur = ext(rA, rB, cur, 3); const float t3 = (float)cur;
        cur = ext(rA, rB, cur, 2); const float t2 = (float)cur;
        cur = ext(rA, rB, cur, 1); const float t1 = (float)cur;
        cur = ext(rA, rB, cur, 0); const float t0 = (float)cur;
        if (l == 0) *(float4*)(outb + 4 * s4) = make_float4(t0, t1, t2, t3);
        qa0 = qa1; qb0 = qb1; qa1 = qa2; qb1 = qb2; qa2 = qa3; qb2 = qb3;
        ld(s4 - 4, qa3, qb3);
    }
}

extern "C" void kernel_launch(void* const* d_in, const int* in_sizes, int n_in,
                              void* d_out, int out_size, void* d_ws, size_t ws_size,
                              hipStream_t stream)
{
    const float* pot   = (const float*)d_in[0];   // [128, 2048, 128] f32
    const float* trans = (const float*)d_in[1];   // [128, 128] f32
    float* out = (float*)d_out;                   // [128, 2048] f32 (tags)

    // ws: bp4 dwords [512][128][128] (32 MiB) then lastTag int[128]
    unsigned* bp4 = (unsigned*)d_ws;
    int* lastTag  = (int*)((char*)d_ws + (size_t)NS4 * B_DIM * C_DIM * 4);

    viterbi_fwd<<<B_DIM / 2, 1024, 0, stream>>>(pot, trans, bp4, lastTag);
    viterbi_bwd<<<B_DIM, 64, 0, stream>>>(bp4, lastTag, out);
}